// Round 3
// baseline (1867.851 us; speedup 1.0000x reference)
//
#include <hip/hip_runtime.h>
#include <hip/hip_bf16.h>
#include <stdint.h>

#define N_IN 250000
#define N_OUT 500000
#define INC 256
#define OUTC 128
#define KVOL 8
#define BN_EPS 1e-5f

typedef __bf16 bf16x8_t __attribute__((ext_vector_type(8)));
typedef __bf16 bf16x4_t __attribute__((ext_vector_type(4)));
typedef float f32x4_t __attribute__((ext_vector_type(4)));

__device__ __forceinline__ __bf16 f2bf(float x) {
  union { float f; uint32_t u; } v; v.f = x;
  uint32_t r = v.u + 0x7FFFu + ((v.u >> 16) & 1u);
  uint16_t h = (uint16_t)(r >> 16);
  union { uint16_t s; __bf16 b; } o; o.s = h;
  return o.b;
}

// pack two f32 -> packed bf16x2 (RNE), lo in bits [15:0], hi in [31:16]
__device__ __forceinline__ uint32_t pack2bf(float lo, float hi) {
  union { float f; uint32_t u; } a, b; a.f = lo; b.f = hi;
  uint32_t ra = a.u + 0x7FFFu + ((a.u >> 16) & 1u);
  uint32_t rb = b.u + 0x7FFFu + ((b.u >> 16) & 1u);
  return (ra >> 16) | (rb & 0xFFFF0000u);
}

// HW packed-bf16 atomic add (device scope), no return value.
__device__ __forceinline__ void atomic_pk_add_bf16(void* addr, uint32_t val) {
  asm volatile("global_atomic_pk_add_bf16 %0, %1, off"
               :: "v"((uint64_t)(uintptr_t)addr), "v"(val)
               : "memory");
}

__device__ __forceinline__ float bflo(uint32_t w) {
  union { uint32_t u; float f; } v; v.u = w << 16; return v.f;
}
__device__ __forceinline__ float bfhi(uint32_t w) {
  union { uint32_t u; float f; } v; v.u = w & 0xFFFF0000u; return v.f;
}

// Convert W[k][inc][outc] (fp32) -> Wt[k][outc][inc] (bf16): MFMA A-operand
// fragments (8 contiguous k-elements per lane) become contiguous 16B loads.
__global__ void wconv_kernel(const float* __restrict__ W, __bf16* __restrict__ Wt) {
  int f = blockIdx.x * blockDim.x + threadIdx.x;
  if (f >= KVOL * OUTC * INC) return;
  int i = f & (INC - 1);
  int o = (f >> 8) & (OUTC - 1);
  int k = f >> 15;
  Wt[f] = f2bf(W[(k * INC + i) * OUTC + o]);
}

#define TM 64          // input rows per block
#define LDS_STRIDE 264 // bf16 elems per LDS row: 256 + 8 pad

// 512 threads = 8 waves. Wave w computes W[w]^T(128x256) x x_tile^T(256x64)
// via bf16 MFMA with SWAPPED operands, so D[chan][voxel]: each lane holds 4
// consecutive channels (reg idx) of one voxel -> packed-bf16 atomics.
// Accumulator layout: bf16[128] in bytes [512*d, 512*d+256) of d_out row d.
__global__ __launch_bounds__(512, 1) void gemm_scatter_kernel(
    const float* __restrict__ x, const __bf16* __restrict__ Wt,
    const int* __restrict__ out_idx, char* __restrict__ accb) {
  __shared__ __bf16 xs[TM * LDS_STRIDE];
  const int t = threadIdx.x;
  const int row0 = blockIdx.x * TM;

  // ---- stage x tile (64 x 256 fp32 -> bf16 LDS), zero-fill OOB rows ----
  #pragma unroll
  for (int i = 0; i < 8; ++i) {
    int f = t + i * 512;      // float4 index within tile (4096 total)
    int r = f >> 6;
    int c4 = f & 63;
    int grow = row0 + r;
    float4 v = make_float4(0.f, 0.f, 0.f, 0.f);
    if (grow < N_IN) v = ((const float4*)x)[(size_t)grow * 64 + c4];
    bf16x4_t bv;
    bv[0] = f2bf(v.x); bv[1] = f2bf(v.y); bv[2] = f2bf(v.z); bv[3] = f2bf(v.w);
    *(bf16x4_t*)&xs[r * LDS_STRIDE + c4 * 4] = bv;
  }
  __syncthreads();

  const int w  = t >> 6;   // wave id == kernel offset k
  const int l  = t & 63;
  const int lr = l & 15;
  const int lg = l >> 4;

  // accT[n][m]: D[chan 16n..][voxel 16m..]; lane holds chan lg*4+reg, voxel lr
  f32x4_t accT[8][4];
  #pragma unroll
  for (int n = 0; n < 8; ++n)
    #pragma unroll
    for (int m = 0; m < 4; ++m)
      accT[n][m] = (f32x4_t){0.f, 0.f, 0.f, 0.f};

  const __bf16* Wk = Wt + (size_t)w * OUTC * INC;  // [128][256] bf16

  #pragma unroll
  for (int s = 0; s < 8; ++s) {   // K in steps of 32
    bf16x8_t a[4], b[8];
    #pragma unroll
    for (int m = 0; m < 4; ++m) {
      int r = m * 16 + lr;
      a[m] = *(const bf16x8_t*)&xs[r * LDS_STRIDE + s * 32 + lg * 8];
    }
    #pragma unroll
    for (int n = 0; n < 8; ++n) {
      int ch = n * 16 + lr;
      b[n] = *(const bf16x8_t*)&Wk[ch * INC + s * 32 + lg * 8];
    }
    // swapped operands: A = W^T tile (chan x k), B = x^T tile (k x voxel)
    #pragma unroll
    for (int n = 0; n < 8; ++n)
      #pragma unroll
      for (int m = 0; m < 4; ++m)
        accT[n][m] = __builtin_amdgcn_mfma_f32_16x16x32_bf16(b[n], a[m], accT[n][m], 0, 0, 0);
  }

  // ---- packed-bf16 atomic scatter ----
  // lane lane-fixed voxel (per m): grow = row0 + m*16 + lr
  // chans: c = n*16 + lg*4 + {0,1,2,3}; byte offset in row = 2*c
  const int* oidx = out_idx + (size_t)w * N_IN;
  #pragma unroll
  for (int m = 0; m < 4; ++m) {
    int grow = row0 + m * 16 + lr;
    if (grow < N_IN) {
      int dst = oidx[grow];
      char* rowp = accb + (size_t)dst * 512 + lg * 8;
      #pragma unroll
      for (int n = 0; n < 8; ++n) {
        uint32_t p0 = pack2bf(accT[n][m][0], accT[n][m][1]);
        uint32_t p1 = pack2bf(accT[n][m][2], accT[n][m][3]);
        atomic_pk_add_bf16(rowp + n * 32, p0);
        atomic_pk_add_bf16(rowp + n * 32 + 4, p1);
      }
    }
  }
}

// Column-wise sum / sum-of-squares over the interleaved bf16 accumulator.
// Thread t: chunk j = t&15 (16B = 8 chans), row offset ro = t>>4.
__global__ void stats_kernel(const char* __restrict__ accb, float* __restrict__ stats) {
  const int t = threadIdx.x;
  const int j = t & 15;
  const int ro = t >> 4;
  float s[8], q[8];
  #pragma unroll
  for (int i = 0; i < 8; ++i) { s[i] = 0.f; q[i] = 0.f; }
  for (int r = blockIdx.x * 16 + ro; r < N_OUT; r += gridDim.x * 16) {
    uint4 v = *(const uint4*)(accb + (size_t)r * 512 + j * 16);
    uint32_t wds[4] = {v.x, v.y, v.z, v.w};
    #pragma unroll
    for (int u = 0; u < 4; ++u) {
      float f0 = bflo(wds[u]), f1 = bfhi(wds[u]);
      s[2 * u] += f0;     q[2 * u] += f0 * f0;
      s[2 * u + 1] += f1; q[2 * u + 1] += f1 * f1;
    }
  }
  __shared__ float reds[16][16][8];
  __shared__ float redq[16][16][8];
  #pragma unroll
  for (int i = 0; i < 8; ++i) { reds[ro][j][i] = s[i]; redq[ro][j][i] = q[i]; }
  __syncthreads();
  if (t < 128) {
    int c = t;                      // channel
    float acc = 0.f;
    #pragma unroll
    for (int r2 = 0; r2 < 16; ++r2) acc += reds[r2][c >> 3][c & 7];
    atomicAdd(&stats[c], acc);
  } else {
    int c = t - 128;
    float acc = 0.f;
    #pragma unroll
    for (int r2 = 0; r2 < 16; ++r2) acc += redq[r2][c >> 3][c & 7];
    atomicAdd(&stats[128 + c], acc);
  }
}

// Read bf16 accum from row slot, write normalized fp32 over the full slot.
// Row-private: each lane reads its 16B then writes its 32B of the same row;
// load issues before store in program order within the wave.
__global__ void norm_kernel(char* __restrict__ outb, const float* __restrict__ stats,
                            const float* __restrict__ gamma, const float* __restrict__ beta) {
  const int t = threadIdx.x;
  const int j = t & 15;
  const int ro = t >> 4;
  const float inv_n = 1.0f / (float)N_OUT;
  float sc[8], sh[8];
  #pragma unroll
  for (int i = 0; i < 8; ++i) {
    int c = j * 8 + i;
    float mean = stats[c] * inv_n;
    float var  = stats[128 + c] * inv_n - mean * mean;
    float s = gamma[c] * rsqrtf(var + BN_EPS);
    sc[i] = s;
    sh[i] = beta[c] - mean * s;
  }
  for (int r = blockIdx.x * 16 + ro; r < N_OUT; r += gridDim.x * 16) {
    uint4 v = *(const uint4*)(outb + (size_t)r * 512 + j * 16);
    uint32_t wds[4] = {v.x, v.y, v.z, v.w};
    f32x4_t o0, o1;
    #pragma unroll
    for (int u = 0; u < 4; ++u) {
      float f0 = bflo(wds[u]) * sc[2 * u] + sh[2 * u];
      float f1 = bfhi(wds[u]) * sc[2 * u + 1] + sh[2 * u + 1];
      if (u < 2) { o0[2 * u] = f0; o0[2 * u + 1] = f1; }
      else       { o1[2 * (u - 2)] = f0; o1[2 * (u - 2) + 1] = f1; }
    }
    *(f32x4_t*)(outb + (size_t)r * 512 + j * 32) = o0;
    *(f32x4_t*)(outb + (size_t)r * 512 + j * 32 + 16) = o1;
  }
}

extern "C" void kernel_launch(void* const* d_in, const int* in_sizes, int n_in,
                              void* d_out, int out_size, void* d_ws, size_t ws_size,
                              hipStream_t stream) {
  const float* x     = (const float*)d_in[0];
  const float* W     = (const float*)d_in[1];
  const float* gamma = (const float*)d_in[2];
  const float* beta  = (const float*)d_in[3];
  const int*   oidx  = (const int*)d_in[4];

  __bf16* Wt   = (__bf16*)d_ws;                                         // 512 KB
  float* stats = (float*)((char*)d_ws + (size_t)KVOL * OUTC * INC * 2); // 1 KB

  hipMemsetAsync(d_out, 0, (size_t)N_OUT * OUTC * sizeof(float), stream);
  hipMemsetAsync(stats, 0, 256 * sizeof(float), stream);

  wconv_kernel<<<(KVOL * OUTC * INC + 255) / 256, 256, 0, stream>>>(W, Wt);
  gemm_scatter_kernel<<<(N_IN + TM - 1) / TM, 512, 0, stream>>>(
      x, Wt, oidx, (char*)d_out);
  stats_kernel<<<256, 256, 0, stream>>>((const char*)d_out, stats);
  norm_kernel<<<512, 256, 0, stream>>>((char*)d_out, stats, gamma, beta);
}

// Round 4
// 918.043 us; speedup vs baseline: 2.0346x; 2.0346x over previous
//
#include <hip/hip_runtime.h>
#include <hip/hip_bf16.h>
#include <stdint.h>

#define N_IN 250000
#define N_OUT 500000
#define INC 256
#define OUTC 128
#define KVOL 8
#define NTOT (KVOL * N_IN)   // 2,000,000 contributions
#define BN_EPS 1e-5f

typedef __bf16 bf16x8_t __attribute__((ext_vector_type(8)));
typedef __bf16 bf16x4_t __attribute__((ext_vector_type(4)));
typedef float f32x4_t __attribute__((ext_vector_type(4)));

__device__ __forceinline__ __bf16 f2bf(float x) {
  union { float f; uint32_t u; } v; v.f = x;
  uint32_t r = v.u + 0x7FFFu + ((v.u >> 16) & 1u);
  uint16_t h = (uint16_t)(r >> 16);
  union { uint16_t s; __bf16 b; } o; o.s = h;
  return o.b;
}

__device__ __forceinline__ uint32_t pack2bf(float lo, float hi) {
  union { float f; uint32_t u; } a, b; a.f = lo; b.f = hi;
  uint32_t ra = a.u + 0x7FFFu + ((a.u >> 16) & 1u);
  uint32_t rb = b.u + 0x7FFFu + ((b.u >> 16) & 1u);
  return (ra >> 16) | (rb & 0xFFFF0000u);
}

__device__ __forceinline__ float bflo(uint32_t w) {
  union { uint32_t u; float f; } v; v.u = w << 16; return v.f;
}
__device__ __forceinline__ float bfhi(uint32_t w) {
  union { uint32_t u; float f; } v; v.u = w & 0xFFFF0000u; return v.f;
}

// W[k][inc][outc] fp32 -> Wt[k][outc][inc] bf16 (contiguous MFMA fragments)
__global__ void wconv_kernel(const float* __restrict__ W, __bf16* __restrict__ Wt) {
  int f = blockIdx.x * blockDim.x + threadIdx.x;
  if (f >= KVOL * OUTC * INC) return;
  int i = f & (INC - 1);
  int o = (f >> 8) & (OUTC - 1);
  int k = f >> 15;
  Wt[f] = f2bf(W[(k * INC + i) * OUTC + o]);
}

// ======================= counting-sort passes =======================

__global__ void hist_kernel(const int* __restrict__ oidx, int* __restrict__ cnt) {
  int g = blockIdx.x * 256 + threadIdx.x;
  if (g < NTOT) atomicAdd(&cnt[oidx[g]], 1);
}

// per-1024-chunk exclusive scan + chunk totals
__global__ void scan1_kernel(const int* __restrict__ cnt, int* __restrict__ offs,
                             int* __restrict__ bsum) {
  __shared__ int sd[256];
  int t = threadIdx.x;
  int base = blockIdx.x * 1024 + t * 4;
  int v0 = 0, v1 = 0, v2 = 0, v3 = 0;
  if (base + 3 < N_OUT) {
    int4 v = *(const int4*)&cnt[base];
    v0 = v.x; v1 = v.y; v2 = v.z; v3 = v.w;
  } else {
    if (base     < N_OUT) v0 = cnt[base];
    if (base + 1 < N_OUT) v1 = cnt[base + 1];
    if (base + 2 < N_OUT) v2 = cnt[base + 2];
  }
  int s = v0 + v1 + v2 + v3;
  sd[t] = s; __syncthreads();
  for (int o = 1; o < 256; o <<= 1) {
    int a = (t >= o) ? sd[t - o] : 0;
    __syncthreads();
    sd[t] += a;
    __syncthreads();
  }
  int excl = sd[t] - s;
  if (base     < N_OUT) offs[base]     = excl;
  if (base + 1 < N_OUT) offs[base + 1] = excl + v0;
  if (base + 2 < N_OUT) offs[base + 2] = excl + v0 + v1;
  if (base + 3 < N_OUT) offs[base + 3] = excl + v0 + v1 + v2;
  if (t == 255) bsum[blockIdx.x] = sd[255];
}

// single-block exclusive scan of chunk totals (nb <= 512)
__global__ void scan2_kernel(const int* __restrict__ bsum, int* __restrict__ bsumx, int nb) {
  __shared__ int sd[512];
  int t = threadIdx.x;
  int s = (t < nb) ? bsum[t] : 0;
  sd[t] = s; __syncthreads();
  for (int o = 1; o < 512; o <<= 1) {
    int a = (t >= o) ? sd[t - o] : 0;
    __syncthreads();
    sd[t] += a;
    __syncthreads();
  }
  if (t < nb) bsumx[t] = sd[t] - s;
}

__global__ void scan3_kernel(int* __restrict__ offs, int* __restrict__ cursor,
                             const int* __restrict__ bsumx) {
  int g = blockIdx.x * 256 + threadIdx.x;
  if (g < N_OUT) {
    int v = offs[g] + bsumx[g >> 10];
    offs[g] = v;
    cursor[g] = v;
  }
  if (g == 0) offs[N_OUT] = NTOT;
}

__global__ void fill_kernel(const int* __restrict__ oidx, int* __restrict__ cursor,
                            int* __restrict__ slot) {
  int g = blockIdx.x * 256 + threadIdx.x;
  if (g < NTOT) {
    int d = oidx[g];
    slot[g] = atomicAdd(&cursor[d], 1);
  }
}

// ======================= GEMM -> sorted partials =======================

#define TM 64
#define LDS_STRIDE 264  // bf16 elems per xs row (256 + 8 pad)

// 512 threads = 8 waves; wave w handles kernel offset k=w. Computes the
// transposed product D[chan][voxel] for a 64-row x tile and writes each
// contribution's 128-chan bf16 row to partials[slot[k*N_IN+i]] with plain
// coalesced 256B stores (LDS-staged transpose; no atomics).
__global__ __launch_bounds__(512, 1) void gemm_store_kernel(
    const float* __restrict__ x, const __bf16* __restrict__ Wt,
    const int* __restrict__ slot, char* __restrict__ partials) {
  __shared__ __bf16 xs[TM * LDS_STRIDE];   // 33792 B
  __shared__ uint2 stg[8][16][34];         // per-wave stage, 272B row stride
  const int t = threadIdx.x;
  const int row0 = blockIdx.x * TM;

  #pragma unroll
  for (int i = 0; i < 8; ++i) {
    int f = t + i * 512;
    int r = f >> 6;
    int c4 = f & 63;
    int grow = row0 + r;
    float4 v = make_float4(0.f, 0.f, 0.f, 0.f);
    if (grow < N_IN) v = ((const float4*)x)[(size_t)grow * 64 + c4];
    bf16x4_t bv;
    bv[0] = f2bf(v.x); bv[1] = f2bf(v.y); bv[2] = f2bf(v.z); bv[3] = f2bf(v.w);
    *(bf16x4_t*)&xs[r * LDS_STRIDE + c4 * 4] = bv;
  }
  __syncthreads();

  const int w  = t >> 6;
  const int l  = t & 63;
  const int lr = l & 15;
  const int lg = l >> 4;

  f32x4_t accT[8][4];
  #pragma unroll
  for (int n = 0; n < 8; ++n)
    #pragma unroll
    for (int m = 0; m < 4; ++m)
      accT[n][m] = (f32x4_t){0.f, 0.f, 0.f, 0.f};

  const __bf16* Wk = Wt + (size_t)w * OUTC * INC;

  #pragma unroll
  for (int s = 0; s < 8; ++s) {
    bf16x8_t a[4], b[8];
    #pragma unroll
    for (int m = 0; m < 4; ++m)
      a[m] = *(const bf16x8_t*)&xs[(m * 16 + lr) * LDS_STRIDE + s * 32 + lg * 8];
    #pragma unroll
    for (int n = 0; n < 8; ++n)
      b[n] = *(const bf16x8_t*)&Wk[(n * 16 + lr) * INC + s * 32 + lg * 8];
    #pragma unroll
    for (int n = 0; n < 8; ++n)
      #pragma unroll
      for (int m = 0; m < 4; ++m)
        accT[n][m] = __builtin_amdgcn_mfma_f32_16x16x32_bf16(b[n], a[m], accT[n][m], 0, 0, 0);
  }

  // stage 16 voxel-rows per m to LDS (bf16), then store 256B rows to partials
  const int r = l >> 2;   // row within 16-row subtile
  const int p = l & 3;    // 64B quarter of the 256B row
  #pragma unroll
  for (int m = 0; m < 4; ++m) {
    // lane (lg,lr) holds voxel lr+16m, chans 16n+4lg+{0..3}
    #pragma unroll
    for (int n = 0; n < 8; ++n) {
      uint2 pk;
      pk.x = pack2bf(accT[n][m][0], accT[n][m][1]);
      pk.y = pack2bf(accT[n][m][2], accT[n][m][3]);
      stg[w][lr][n * 4 + lg] = pk;
    }
    __syncthreads();
    int grow = row0 + 16 * m + r;
    if (grow < N_IN) {
      int sl = slot[w * N_IN + grow];
      const uint4* rp = (const uint4*)&stg[w][r][0];
      char* dst = partials + (size_t)sl * 256 + p * 64;
      #pragma unroll
      for (int q = 0; q < 4; ++q)
        *(uint4*)(dst + q * 16) = rp[p * 4 + q];
    }
    __syncthreads();
  }
}

// ============== segmented reduce + fused BN stats ==============

// 256 thr = 16 groups x 16 lanes; group handles one output row at a time:
// sums its contiguous partials, writes bf16 accum into d_out slot, and
// accumulates per-channel sum/sumsq (over the rounded bf16 values).
__global__ __launch_bounds__(256) void reduce_stats_kernel(
    const char* __restrict__ partials, const int* __restrict__ offs,
    char* __restrict__ accb, float* __restrict__ stats) {
  const int t = threadIdx.x;
  const int lane16 = t & 15;
  const int grp = t >> 4;
  float s[8], q[8];
  #pragma unroll
  for (int i = 0; i < 8; ++i) { s[i] = 0.f; q[i] = 0.f; }

  for (int d = blockIdx.x * 16 + grp; d < N_OUT; d += gridDim.x * 16) {
    int j0 = offs[d], j1 = offs[d + 1];
    float a[8];
    #pragma unroll
    for (int i = 0; i < 8; ++i) a[i] = 0.f;
    for (int j = j0; j < j1; ++j) {
      uint4 v = *(const uint4*)(partials + (size_t)j * 256 + lane16 * 16);
      a[0] += bflo(v.x); a[1] += bfhi(v.x);
      a[2] += bflo(v.y); a[3] += bfhi(v.y);
      a[4] += bflo(v.z); a[5] += bfhi(v.z);
      a[6] += bflo(v.w); a[7] += bfhi(v.w);
    }
    uint4 o;
    o.x = pack2bf(a[0], a[1]); o.y = pack2bf(a[2], a[3]);
    o.z = pack2bf(a[4], a[5]); o.w = pack2bf(a[6], a[7]);
    *(uint4*)(accb + (size_t)d * 512 + lane16 * 16) = o;
    uint32_t wd[4] = {o.x, o.y, o.z, o.w};
    #pragma unroll
    for (int u = 0; u < 4; ++u) {
      float f0 = bflo(wd[u]), f1 = bfhi(wd[u]);
      s[2 * u] += f0;     q[2 * u] += f0 * f0;
      s[2 * u + 1] += f1; q[2 * u + 1] += f1 * f1;
    }
  }

  __shared__ float reds[16][16][8];
  __shared__ float redq[16][16][8];
  #pragma unroll
  for (int i = 0; i < 8; ++i) { reds[grp][lane16][i] = s[i]; redq[grp][lane16][i] = q[i]; }
  __syncthreads();
  if (t < 128) {
    float acc = 0.f;
    #pragma unroll
    for (int g2 = 0; g2 < 16; ++g2) acc += reds[g2][t >> 3][t & 7];
    atomicAdd(&stats[t], acc);
  } else {
    int c = t - 128;
    float acc = 0.f;
    #pragma unroll
    for (int g2 = 0; g2 < 16; ++g2) acc += redq[g2][c >> 3][c & 7];
    atomicAdd(&stats[128 + c], acc);
  }
}

// Read bf16 accum from row slot, write normalized fp32 over the full slot.
__global__ void norm_kernel(char* __restrict__ outb, const float* __restrict__ stats,
                            const float* __restrict__ gamma, const float* __restrict__ beta) {
  const int t = threadIdx.x;
  const int j = t & 15;
  const int ro = t >> 4;
  const float inv_n = 1.0f / (float)N_OUT;
  float sc[8], sh[8];
  #pragma unroll
  for (int i = 0; i < 8; ++i) {
    int c = j * 8 + i;
    float mean = stats[c] * inv_n;
    float var  = stats[128 + c] * inv_n - mean * mean;
    float s = gamma[c] * rsqrtf(var + BN_EPS);
    sc[i] = s;
    sh[i] = beta[c] - mean * s;
  }
  for (int r = blockIdx.x * 16 + ro; r < N_OUT; r += gridDim.x * 16) {
    uint4 v = *(const uint4*)(outb + (size_t)r * 512 + j * 16);
    uint32_t wds[4] = {v.x, v.y, v.z, v.w};
    f32x4_t o0, o1;
    #pragma unroll
    for (int u = 0; u < 4; ++u) {
      float f0 = bflo(wds[u]) * sc[2 * u] + sh[2 * u];
      float f1 = bfhi(wds[u]) * sc[2 * u + 1] + sh[2 * u + 1];
      if (u < 2) { o0[2 * u] = f0; o0[2 * u + 1] = f1; }
      else       { o1[2 * (u - 2)] = f0; o1[2 * (u - 2) + 1] = f1; }
    }
    *(f32x4_t*)(outb + (size_t)r * 512 + j * 32) = o0;
    *(f32x4_t*)(outb + (size_t)r * 512 + j * 32 + 16) = o1;
  }
}

// ======================= fallback (round-2 proven path) =======================

__global__ __launch_bounds__(512, 1) void gemm_scatter_f32_kernel(
    const float* __restrict__ x, const __bf16* __restrict__ Wt,
    const int* __restrict__ out_idx, float* __restrict__ acc) {
  __shared__ __bf16 xs[TM * LDS_STRIDE];
  const int t = threadIdx.x;
  const int row0 = blockIdx.x * TM;
  #pragma unroll
  for (int i = 0; i < 8; ++i) {
    int f = t + i * 512;
    int r = f >> 6;
    int c4 = f & 63;
    int grow = row0 + r;
    float4 v = make_float4(0.f, 0.f, 0.f, 0.f);
    if (grow < N_IN) v = ((const float4*)x)[(size_t)grow * 64 + c4];
    bf16x4_t bv;
    bv[0] = f2bf(v.x); bv[1] = f2bf(v.y); bv[2] = f2bf(v.z); bv[3] = f2bf(v.w);
    *(bf16x4_t*)&xs[r * LDS_STRIDE + c4 * 4] = bv;
  }
  __syncthreads();
  const int w = t >> 6, l = t & 63, lr = l & 15, lg = l >> 4;
  f32x4_t accr[4][8];
  #pragma unroll
  for (int m = 0; m < 4; ++m)
    #pragma unroll
    for (int n = 0; n < 8; ++n)
      accr[m][n] = (f32x4_t){0.f, 0.f, 0.f, 0.f};
  const __bf16* Wk = Wt + (size_t)w * OUTC * INC;
  #pragma unroll
  for (int s = 0; s < 8; ++s) {
    bf16x8_t a[4], b[8];
    #pragma unroll
    for (int m = 0; m < 4; ++m)
      a[m] = *(const bf16x8_t*)&xs[(m * 16 + lr) * LDS_STRIDE + s * 32 + lg * 8];
    #pragma unroll
    for (int n = 0; n < 8; ++n)
      b[n] = *(const bf16x8_t*)&Wk[(n * 16 + lr) * INC + s * 32 + lg * 8];
    #pragma unroll
    for (int m = 0; m < 4; ++m)
      #pragma unroll
      for (int n = 0; n < 8; ++n)
        accr[m][n] = __builtin_amdgcn_mfma_f32_16x16x32_bf16(a[m], b[n], accr[m][n], 0, 0, 0);
  }
  const int* oidx = out_idx + (size_t)w * N_IN;
  #pragma unroll
  for (int m = 0; m < 4; ++m) {
    int rbase = m * 16 + lg * 4;
    #pragma unroll
    for (int reg = 0; reg < 4; ++reg) {
      int grow = row0 + rbase + reg;
      if (grow < N_IN) {
        int dst = oidx[grow];
        float* ap = acc + (size_t)dst * OUTC;
        #pragma unroll
        for (int n = 0; n < 8; ++n)
          atomicAdd(&ap[n * 16 + lr], accr[m][n][reg]);
      }
    }
  }
}

__global__ void stats_f32_kernel(const float* __restrict__ acc, float* __restrict__ stats) {
  const int t = threadIdx.x;
  const int c4 = t & 31;
  const int ro = t >> 5;
  f32x4_t s = {0.f, 0.f, 0.f, 0.f}, q = {0.f, 0.f, 0.f, 0.f};
  for (int r = blockIdx.x * 8 + ro; r < N_OUT; r += gridDim.x * 8) {
    f32x4_t v = ((const f32x4_t*)acc)[(size_t)r * 32 + c4];
    s += v; q += v * v;
  }
  __shared__ float red[256][8];
  #pragma unroll
  for (int j = 0; j < 4; ++j) { red[t][j] = s[j]; red[t][4 + j] = q[j]; }
  __syncthreads();
  if (t < 32) {
    float S[4] = {0.f, 0.f, 0.f, 0.f}, Q[4] = {0.f, 0.f, 0.f, 0.f};
    for (int r2 = 0; r2 < 8; ++r2)
      #pragma unroll
      for (int j = 0; j < 4; ++j) {
        S[j] += red[r2 * 32 + t][j];
        Q[j] += red[r2 * 32 + t][4 + j];
      }
    #pragma unroll
    for (int j = 0; j < 4; ++j) {
      atomicAdd(&stats[t * 4 + j], S[j]);
      atomicAdd(&stats[128 + t * 4 + j], Q[j]);
    }
  }
}

__global__ void norm_f32_kernel(float* __restrict__ out, const float* __restrict__ stats,
                                const float* __restrict__ gamma, const float* __restrict__ beta) {
  const int t = threadIdx.x;
  const int c4 = t & 31;
  const int ro = t >> 5;
  const float inv_n = 1.0f / (float)N_OUT;
  float sc[4], sh[4];
  #pragma unroll
  for (int j = 0; j < 4; ++j) {
    int c = c4 * 4 + j;
    float mean = stats[c] * inv_n;
    float var  = stats[128 + c] * inv_n - mean * mean;
    float s = gamma[c] * rsqrtf(var + BN_EPS);
    sc[j] = s;
    sh[j] = beta[c] - mean * s;
  }
  for (int r = blockIdx.x * 8 + ro; r < N_OUT; r += gridDim.x * 8) {
    f32x4_t v = ((const f32x4_t*)out)[(size_t)r * 32 + c4];
    #pragma unroll
    for (int j = 0; j < 4; ++j) v[j] = v[j] * sc[j] + sh[j];
    ((f32x4_t*)out)[(size_t)r * 32 + c4] = v;
  }
}

// ======================= launch =======================

extern "C" void kernel_launch(void* const* d_in, const int* in_sizes, int n_in,
                              void* d_out, int out_size, void* d_ws, size_t ws_size,
                              hipStream_t stream) {
  const float* x     = (const float*)d_in[0];
  const float* W     = (const float*)d_in[1];
  const float* gamma = (const float*)d_in[2];
  const float* beta  = (const float*)d_in[3];
  const int*   oidx  = (const int*)d_in[4];

  // ws layout (path C)
  const size_t P_OFF     = 0;                       // partials: 512,000,000
  const size_t SLOT_OFF  = 512000000;               // 8,000,000
  const size_t CNT_OFF   = 520000000;               // 2,000,000
  const size_t OFFS_OFF  = 522000000;               // 2,000,384 (500001 ints + pad)
  const size_t CURS_OFF  = 524000384;               // 2,000,000
  const size_t BSUM_OFF  = 526000384;               // 4,096
  const size_t BSUMX_OFF = 526004480;               // 4,096
  const size_t WT_OFF    = 526008576;               // 524,288
  const size_t STATS_OFF = 526532864;               // 1,024
  const size_t NEED      = 526533888;

  if (ws_size >= NEED) {
    char* ws = (char*)d_ws;
    char* partials = ws + P_OFF;
    int* slot   = (int*)(ws + SLOT_OFF);
    int* cnt    = (int*)(ws + CNT_OFF);
    int* offs   = (int*)(ws + OFFS_OFF);
    int* cursor = (int*)(ws + CURS_OFF);
    int* bsum   = (int*)(ws + BSUM_OFF);
    int* bsumx  = (int*)(ws + BSUMX_OFF);
    __bf16* Wt  = (__bf16*)(ws + WT_OFF);
    float* stats = (float*)(ws + STATS_OFF);

    hipMemsetAsync(cnt, 0, N_OUT * sizeof(int), stream);
    hipMemsetAsync(stats, 0, 256 * sizeof(float), stream);

    wconv_kernel<<<(KVOL * OUTC * INC + 255) / 256, 256, 0, stream>>>(W, Wt);
    hist_kernel<<<(NTOT + 255) / 256, 256, 0, stream>>>(oidx, cnt);
    const int NB1 = (N_OUT + 1023) / 1024;  // 489
    scan1_kernel<<<NB1, 256, 0, stream>>>(cnt, offs, bsum);
    scan2_kernel<<<1, 512, 0, stream>>>(bsum, bsumx, NB1);
    scan3_kernel<<<(N_OUT + 255) / 256, 256, 0, stream>>>(offs, cursor, bsumx);
    fill_kernel<<<(NTOT + 255) / 256, 256, 0, stream>>>(oidx, cursor, slot);
    gemm_store_kernel<<<(N_IN + TM - 1) / TM, 512, 0, stream>>>(x, Wt, slot, partials);
    reduce_stats_kernel<<<2048, 256, 0, stream>>>(partials, offs, (char*)d_out, stats);
    norm_kernel<<<512, 256, 0, stream>>>((char*)d_out, stats, gamma, beta);
  } else {
    // fallback: proven round-2 atomic pipeline (needs only ~526 KB ws)
    __bf16* Wt   = (__bf16*)d_ws;
    float* stats = (float*)((char*)d_ws + (size_t)KVOL * OUTC * INC * 2);
    float* out = (float*)d_out;

    hipMemsetAsync(d_out, 0, (size_t)N_OUT * OUTC * sizeof(float), stream);
    hipMemsetAsync(stats, 0, 256 * sizeof(float), stream);

    wconv_kernel<<<(KVOL * OUTC * INC + 255) / 256, 256, 0, stream>>>(W, Wt);
    gemm_scatter_f32_kernel<<<(N_IN + TM - 1) / TM, 512, 0, stream>>>(x, Wt, oidx, out);
    stats_f32_kernel<<<1024, 256, 0, stream>>>(out, stats);
    norm_f32_kernel<<<2048, 256, 0, stream>>>(out, stats, gamma, beta);
  }
}